// Round 10
// baseline (1292.395 us; speedup 1.0000x reference)
//
#include <hip/hip_runtime.h>
#include <cstdint>
#include <cstddef>

// ---------------------------------------------------------------------------
// AffineMultiQueryHardAttentionEncoder
//   scores[m] = max_n ( (q[n]*a) . k[m] ), top-64, softmax, sum w_i * V[idx_i]
// R10 = R9 with the spill fixed and the A-stream paced.
//   - __launch_bounds__(512,1): 256-VGPR cap (R9's (512,2) forced 128 ->
//     ~80 spilled regs -> 20MB scratch traffic -> 384us).
//   - A-loads: ONE f32x4 per thread issued at the top of each of the first
//     24 sub-steps (p-loop fully unrolled, static Qf index). Each is drained
//     ~1 sub-step later by WRITE_B's in-order vmcnt wait -> continuous
//     paced HBM stream instead of burst+starve.
//   - everything else identical to R9 (lgkm-only barriers, B reg-dbuf,
//     per-half epilogue, hist/rescore/final tail).
// ---------------------------------------------------------------------------

typedef __attribute__((ext_vector_type(8))) short bf16x8;
typedef __attribute__((ext_vector_type(4))) float f32x4;

static constexpr int NQ = 512;
static constexpr int DD = 1024;
static constexpr int MK = 100000;
static constexpr int NTILES = 1042;          // ceil(100000 / 96)
static constexpr int CAP = 1024;

// workspace layout (bytes)
static constexpr size_t QSTAGE_OFF   = 0;    // [32 ks][4 g][512 q][16B] = 1 MiB
static constexpr size_t QSTAGE_BYTES = (size_t)32 * 4 * NQ * 16;
static constexpr size_t SCORES_OFF   = QSTAGE_OFF + QSTAGE_BYTES;
static constexpr size_t SCORES_BYTES = (size_t)100032 * 4;
static constexpr size_t CIDX_OFF     = SCORES_OFF + SCORES_BYTES;
static constexpr size_t RESC_OFF     = CIDX_OFF + (size_t)CAP * 4;
static constexpr size_t CNT_OFF      = RESC_OFF + (size_t)CAP * 4;
static constexpr size_t HIST_OFF     = CNT_OFF + 64;
static constexpr size_t VLO_OFF      = HIST_OFF + 8192 * 4;

// gemm LDS: A [48 rows][2048B] = 98304 @0 ; B dbuf 2x32768 @98304 -> 163840
static constexpr int GEMM_LDS = 98304 + 2 * 32768;   // exactly 160 KiB

static __device__ __forceinline__ unsigned short f32_to_bf16_rne(float f) {
    unsigned int u = __float_as_uint(f);
    unsigned int r = (u + 0x7FFFu + ((u >> 16) & 1u)) >> 16;
    return (unsigned short)r;
}
static __device__ __forceinline__ unsigned int xform(float f) {
    unsigned int u = __float_as_uint(f);
    return u ^ ((unsigned int)((int)u >> 31) | 0x80000000u);
}
static __device__ __forceinline__ float unxform(unsigned int u) {
    unsigned int b = (u & 0x80000000u) ? (u ^ 0x80000000u) : ~u;
    return __uint_as_float(b);
}

// ---------------------------------------------------------------------------
// prep_q: qa = q*a -> bf16 RNE, fragment-major:
//   chunk id = (ks*4 + g)*512 + q   holds   qa[q][ks*32 + g*8 .. +7]
// ---------------------------------------------------------------------------
__global__ void prep_q(const float* __restrict__ q, const float* __restrict__ a,
                       unsigned short* __restrict__ qs) {
    int id = blockIdx.x * 256 + threadIdx.x;    // 0..65535
    int qq = id & 511;
    int g  = (id >> 9) & 3;
    int ks = id >> 11;
    int col = ks * 32 + g * 8;

    const float* qrow = q + (size_t)qq * DD + col;
    float4 v0 = *(const float4*)(qrow);
    float4 v1 = *(const float4*)(qrow + 4);
    float4 a0 = *(const float4*)(a + col);
    float4 a1 = *(const float4*)(a + col + 4);
    float f[8] = {v0.x * a0.x, v0.y * a0.y, v0.z * a0.z, v0.w * a0.w,
                  v1.x * a1.x, v1.y * a1.y, v1.z * a1.z, v1.w * a1.w};
    bf16x8 o;
#pragma unroll
    for (int t = 0; t < 8; ++t) o[t] = (short)f32_to_bf16_rne(f[t]);
    *(bf16x8*)(qs + (size_t)id * 8) = o;
}

// ---------------------------------------------------------------------------
// persistent prescreen GEMM + column max
// ---------------------------------------------------------------------------
__launch_bounds__(512, 1)
__global__ void scores_gemm(const float* __restrict__ keys,
                            const unsigned short* __restrict__ qs,
                            float* __restrict__ scores) {
    extern __shared__ char smem[];
    const int tid = threadIdx.x;
    const int w   = tid >> 6;
    const int l   = tid & 63;
    const int g   = l >> 4;
    const int r16 = l & 15;
    const int r7  = r16 & 7;
    const int b   = blockIdx.x;          // 0..255, 1 block/CU

    const int ntile = (NTILES - b + 255) >> 8;   // 4 or 5 tiles
    const int nhalf = ntile * 2;

    char* const al = smem;                       // A tile
    char* const bl = smem + 98304;               // B dbuf
    float* const wmax = (float*)(bl + 32768);    // overlays B buf1 (free at epilogue)

    const char* const qsl = (const char*)qs + (size_t)(w * 64 + l) * 16;
    const int bwr = (w * 64 + l) * 16;           // B ds_write lane offset (+g*8192)

    int abase[3];
#pragma unroll
    for (int rt = 0; rt < 3; ++rt) abase[rt] = (rt * 16 + r16) * 2048;
    int bqoff[4];
#pragma unroll
    for (int ct = 0; ct < 4; ++ct) bqoff[ct] = ((w * 4 + ct) * 16 + r16) * 16;

    f32x4 acc[3][4];
#pragma unroll
    for (int rt = 0; rt < 3; ++rt)
#pragma unroll
        for (int ct = 0; ct < 4; ++ct)
#pragma unroll
            for (int j = 0; j < 4; ++j) acc[rt][ct][j] = 0.f;

    f32x4 Qf[24];        // next-half A staging (f32) -- statically indexed only
    f32x4 RbA[4], RbB[4];// B reg staging (2 sub-steps ahead)

#define ROWBASE(H) ((b + ((H) >> 1) * 256) * 96 + ((H) & 1) * 48)

// one A f32x4 per thread, static index I, rows from BASE
#define LOAD_A1(I, BASE) do {                                                  \
    int gc_ = (I) * 512 + tid;                                                 \
    int grow_ = (BASE) + (gc_ >> 8);                                           \
    if (grow_ > MK - 1) grow_ = MK - 1;                                        \
    Qf[I] = *(const f32x4*)(keys + (size_t)grow_ * 1024 + (gc_ & 255) * 4);    \
} while (0)

#define LOAD_AH(BASE) do {                                                     \
    _Pragma("unroll")                                                          \
    for (int i_ = 0; i_ < 24; ++i_) LOAD_A1(i_, BASE);                         \
} while (0)

#define WRITE_AH() do {                                                        \
    _Pragma("unroll")                                                          \
    for (int i_ = 0; i_ < 24; ++i_) {                                          \
        int gc_ = i_ * 512 + tid;                                              \
        int row_ = gc_ >> 8;                                                   \
        int c16_ = (gc_ & 255) >> 1;                                           \
        unsigned long long pk_ =                                               \
            (unsigned long long)f32_to_bf16_rne(Qf[i_].x)                      \
          | ((unsigned long long)f32_to_bf16_rne(Qf[i_].y) << 16)              \
          | ((unsigned long long)f32_to_bf16_rne(Qf[i_].z) << 32)              \
          | ((unsigned long long)f32_to_bf16_rne(Qf[i_].w) << 48);             \
        *(unsigned long long*)(al + row_ * 2048 +                              \
            ((c16_ ^ (row_ & 7)) << 4) + (gc_ & 1) * 8) = pk_;                 \
    }                                                                          \
} while (0)

#define LOAD_B(R, KS2) do {                                                    \
    _Pragma("unroll")                                                          \
    for (int g2 = 0; g2 < 4; ++g2)                                             \
        R[g2] = *(const f32x4*)(qsl + (size_t)(((KS2) * 4 + g2) * 512) * 16);  \
} while (0)

#define WRITE_B(R, NXT) do {                                                   \
    _Pragma("unroll")                                                          \
    for (int g2 = 0; g2 < 4; ++g2)                                             \
        *(f32x4*)(bl + (NXT) * 32768 + g2 * 8192 + bwr) = R[g2];               \
} while (0)

#define MFMA_STEP(KS, CUR) do {                                                \
    const int chunk_ = ((((KS) * 4) + g) ^ r7) << 4;                           \
    bf16x8 af[3], bfr[4];                                                      \
    _Pragma("unroll")                                                          \
    for (int rt = 0; rt < 3; ++rt)                                             \
        af[rt] = *(const bf16x8*)(al + abase[rt] + chunk_);                    \
    _Pragma("unroll")                                                          \
    for (int ct = 0; ct < 4; ++ct)                                             \
        bfr[ct] = *(const bf16x8*)(bl + (CUR) * 32768 + g * 8192 + bqoff[ct]); \
    __builtin_amdgcn_s_setprio(1);                                             \
    _Pragma("unroll")                                                          \
    for (int rt = 0; rt < 3; ++rt)                                             \
        _Pragma("unroll")                                                      \
        for (int ct = 0; ct < 4; ++ct)                                         \
            acc[rt][ct] = __builtin_amdgcn_mfma_f32_16x16x32_bf16(             \
                af[rt], bfr[ct], acc[rt][ct], 0, 0, 0);                        \
    __builtin_amdgcn_s_setprio(0);                                             \
} while (0)

#define BAR() do {                                                             \
    asm volatile("s_waitcnt lgkmcnt(0)" ::: "memory");                         \
    __builtin_amdgcn_s_barrier();                                              \
    __builtin_amdgcn_sched_barrier(0);                                         \
} while (0)

    // ---- prologue: A(half0) + B(0) staged, B(1) in regs
    LOAD_AH(ROWBASE(0));
    LOAD_B(RbA, 0);
    LOAD_B(RbB, 1);
    WRITE_AH();             // auto vmcnt wait on A loads
    WRITE_B(RbA, 0);
    __syncthreads();

    for (int half = 0; half < nhalf; ++half) {
        const bool lastH = (half == nhalf - 1);
        const int  baseN = ROWBASE(half + 1);    // rows of NEXT half

#pragma unroll
        for (int p = 0; p < 16; ++p) {
            const int s0 = 2 * p, s1 = 2 * p + 1;
            // even sub-step: paced A-load, buf0 compute, write B(s0+1)
            if (!lastH && s0 < 24) LOAD_A1(s0, baseN);
            if (!(lastH && s0 >= 30)) LOAD_B(RbA, (s0 + 2) & 31);
            MFMA_STEP(s0, 0);
            __builtin_amdgcn_sched_barrier(0);
            WRITE_B(RbB, 1);
            BAR();
            // odd sub-step: paced A-load, buf1 compute, write B(s1+1)
            if (!lastH && s1 < 24) LOAD_A1(s1, baseN);
            if (!(lastH && s1 >= 30)) LOAD_B(RbB, (s1 + 2) & 31);
            MFMA_STEP(s1, 1);
            __builtin_amdgcn_sched_barrier(0);
            if (!(lastH && s1 == 31)) WRITE_B(RbA, 0);
            BAR();
        }

        // ---- half epilogue: stage next A, extract this half's 48 scores
        if (!lastH) WRITE_AH();
#pragma unroll
        for (int rt = 0; rt < 3; ++rt) {
#pragma unroll
            for (int j = 0; j < 4; ++j) {
                float mx = acc[rt][0][j];
                mx = fmaxf(mx, acc[rt][1][j]);
                mx = fmaxf(mx, acc[rt][2][j]);
                mx = fmaxf(mx, acc[rt][3][j]);
#pragma unroll
                for (int off = 1; off < 16; off <<= 1)
                    mx = fmaxf(mx, __shfl_xor(mx, off));
                if (r16 == 0) wmax[w * 48 + rt * 16 + g * 4 + j] = mx;
            }
        }
        BAR();
        {
            const int m0h = ROWBASE(half);
            if (tid < 48) {
                float mx = wmax[tid];
#pragma unroll
                for (int ww = 1; ww < 8; ++ww) mx = fmaxf(mx, wmax[ww * 48 + tid]);
                int gm = m0h + tid;
                if (gm < MK) scores[gm] = mx;
            }
        }
        BAR();   // protect wmax region (B buf1) before next half's ds_writes
#pragma unroll
        for (int rt = 0; rt < 3; ++rt)
#pragma unroll
            for (int ct = 0; ct < 4; ++ct)
#pragma unroll
                for (int j = 0; j < 4; ++j) acc[rt][ct][j] = 0.f;
    }

#undef ROWBASE
#undef LOAD_A1
#undef LOAD_AH
#undef WRITE_AH
#undef LOAD_B
#undef WRITE_B
#undef MFMA_STEP
#undef BAR
}

// ---------------------------------------------------------------------------
// threshold select, multi-block (unchanged)
// ---------------------------------------------------------------------------
__global__ void zero_hist(unsigned int* __restrict__ hist, int* __restrict__ cnt) {
    int i = blockIdx.x * 1024 + threadIdx.x;
    if (i < 8192) hist[i] = 0;
    if (i == 0) cnt[0] = 0;
}

__global__ void hist_build(const float* __restrict__ scores, unsigned int* __restrict__ hist) {
    __shared__ unsigned int lh[8192];
    for (int i = threadIdx.x; i < 8192; i += 256) lh[i] = 0;
    __syncthreads();
    for (int i = blockIdx.x * 256 + threadIdx.x; i < MK; i += gridDim.x * 256)
        atomicAdd(&lh[xform(scores[i]) >> 19], 1u);
    __syncthreads();
    for (int i = threadIdx.x; i < 8192; i += 256) {
        unsigned int c = lh[i];
        if (c) atomicAdd(&hist[i], c);
    }
}

__launch_bounds__(1024)
__global__ void find_thresh(const unsigned int* __restrict__ hist, float* __restrict__ vlo) {
    __shared__ unsigned int s0[1024], s1[1024];
    const int tid = threadIdx.x;
    unsigned int s = 0;
#pragma unroll
    for (int j = 0; j < 8; ++j) s += hist[tid * 8 + j];
    s0[tid] = s;
    __syncthreads();
    unsigned int* src = s0;
    unsigned int* dst = s1;
    for (int off = 1; off < 1024; off <<= 1) {
        unsigned int v = src[tid] + ((tid + off < 1024) ? src[tid + off] : 0u);
        __syncthreads();
        dst[tid] = v;
        __syncthreads();
        unsigned int* t = src; src = dst; dst = t;
    }
    unsigned int suf  = src[tid];
    unsigned int sufn = (tid < 1023) ? src[tid + 1] : 0u;
    if (suf >= 64u && sufn < 64u) {
        unsigned int acc = sufn;
        int b = tid * 8 + 7;
        for (;; --b) { acc += hist[b]; if (acc >= 64u) break; }
        vlo[0] = unxform(((unsigned int)b) << 19) - 1.0f;   // margin 1.0
    }
}

__global__ void collect(const float* __restrict__ scores, const float* __restrict__ vlo,
                        int* __restrict__ cidx, int* __restrict__ cnt) {
    const float t = vlo[0];
    for (int i = blockIdx.x * 256 + threadIdx.x; i < MK; i += gridDim.x * 256) {
        if (scores[i] >= t) {
            int p = atomicAdd(cnt, 1);
            if (p < CAP) cidx[p] = i;
        }
    }
}

// ---------------------------------------------------------------------------
// exact f32 rescore: one block per candidate, max over 512 queries
// ---------------------------------------------------------------------------
__launch_bounds__(256)
__global__ void rescore(const float* __restrict__ q, const float* __restrict__ a,
                        const float* __restrict__ keys,
                        const int* __restrict__ cidx, const int* __restrict__ cnt,
                        float* __restrict__ resc) {
    __shared__ float wsm[1024];
    __shared__ float smax[4];
    const int b = blockIdx.x;
    if (b >= cnt[0]) return;
    const int m   = cidx[b];
    const int tid = threadIdx.x;

    for (int d = tid; d < 1024; d += 256) wsm[d] = a[d] * keys[(size_t)m * DD + d];
    __syncthreads();

    const int wid = tid >> 6, lane = tid & 63;
    float best = -__builtin_inff();
    for (int n = wid; n < NQ; n += 4) {
        const float* qr = q + (size_t)n * DD;
        float p = 0.f;
#pragma unroll
        for (int j = 0; j < 4; ++j) {
            float4 v  = *(const float4*)(qr + lane * 4 + 256 * j);
            float4 ww = *(const float4*)(&wsm[lane * 4 + 256 * j]);
            p += v.x * ww.x + v.y * ww.y + v.z * ww.z + v.w * ww.w;
        }
#pragma unroll
        for (int off = 1; off < 64; off <<= 1) p += __shfl_xor(p, off);
        best = fmaxf(best, p);
    }
    if (lane == 0) smax[wid] = best;
    __syncthreads();
    if (tid == 0)
        resc[b] = fmaxf(fmaxf(smax[0], smax[1]), fmaxf(smax[2], smax[3]));
}

// ---------------------------------------------------------------------------
// final: top-64 over candidates (exact vals, tie: idx asc), softmax, gather V
// ---------------------------------------------------------------------------
__launch_bounds__(256)
__global__ void final_select(const int* __restrict__ cidx, const float* __restrict__ resc,
                             const int* __restrict__ cnt, const float* __restrict__ values,
                             float* __restrict__ out) {
    __shared__ float selw[64];
    __shared__ int   seli[64];
    const int tid = threadIdx.x;
    int nc = cnt[0];
    if (nc > CAP) nc = CAP;

    if (tid < 64) {
        const int lane = tid;
        float lv[16]; int li[16];
#pragma unroll
        for (int j = 0; j < 16; ++j) {
            int slot = lane + 64 * j;
            bool ok = slot < nc;
            lv[j] = ok ? resc[slot] : -__builtin_inff();
            li[j] = ok ? cidx[slot] : 0x7fffffff;
        }
        for (int it = 0; it < 64; ++it) {
            float bv = -__builtin_inff();
            int bg = 0x7fffffff, bj = 0;
#pragma unroll
            for (int j = 0; j < 16; ++j)
                if (lv[j] > bv || (lv[j] == bv && li[j] < bg)) { bv = lv[j]; bg = li[j]; bj = j; }
            int bcode = (lane << 4) | bj;
#pragma unroll
            for (int off = 1; off < 64; off <<= 1) {
                float ov = __shfl_xor(bv, off);
                int   og = __shfl_xor(bg, off);
                int   oc = __shfl_xor(bcode, off);
                if (ov > bv || (ov == bv && og < bg)) { bv = ov; bg = og; bcode = oc; }
            }
            if ((bcode >> 4) == lane) {
                int wj = bcode & 15;
#pragma unroll
                for (int j = 0; j < 16; ++j) if (j == wj) lv[j] = -__builtin_inff();
            }
            if (lane == 0) { selw[it] = bv; seli[it] = bg; }
        }
    }
    __syncthreads();

    if (tid < 64) {
        float x = selw[tid];
        float mx = x;
#pragma unroll
        for (int off = 1; off < 64; off <<= 1) mx = fmaxf(mx, __shfl_xor(mx, off));
        float e = expf(x - mx);
        float s = e;
#pragma unroll
        for (int off = 1; off < 64; off <<= 1) s += __shfl_xor(s, off);
        selw[tid] = e / s;
        out[DD + tid] = (float)seli[tid];
    }
    __syncthreads();

    for (int d = tid; d < DD; d += 256) {
        float accv = 0.f;
        for (int i = 0; i < 64; ++i)
            accv += selw[i] * values[(size_t)seli[i] * DD + d];
        out[d] = accv;
    }
}

// ---------------------------------------------------------------------------
extern "C" void kernel_launch(void* const* d_in, const int* in_sizes, int n_in,
                              void* d_out, int out_size, void* d_ws, size_t ws_size,
                              hipStream_t stream) {
    (void)in_sizes; (void)n_in; (void)out_size; (void)ws_size;
    const float* queries = (const float*)d_in[0];
    const float* keys    = (const float*)d_in[1];
    const float* values  = (const float*)d_in[2];
    const float* affine  = (const float*)d_in[3];
    float* out = (float*)d_out;
    char*  ws  = (char*)d_ws;

    unsigned short* qstage = (unsigned short*)(ws + QSTAGE_OFF);
    float* scores = (float*)(ws + SCORES_OFF);
    int*   cidx   = (int*)(ws + CIDX_OFF);
    float* resc   = (float*)(ws + RESC_OFF);
    int*   cnt    = (int*)(ws + CNT_OFF);
    unsigned int* hist = (unsigned int*)(ws + HIST_OFF);
    float* vlo    = (float*)(ws + VLO_OFF);

    hipFuncSetAttribute((const void*)scores_gemm,
                        hipFuncAttributeMaxDynamicSharedMemorySize, GEMM_LDS);

    prep_q<<<256, 256, 0, stream>>>(queries, affine, qstage);
    scores_gemm<<<256, 512, GEMM_LDS, stream>>>(keys, qstage, scores);
    zero_hist<<<8, 1024, 0, stream>>>(hist, cnt);
    hist_build<<<64, 256, 0, stream>>>(scores, hist);
    find_thresh<<<1, 1024, 0, stream>>>(hist, vlo);
    collect<<<200, 256, 0, stream>>>(scores, vlo, cidx, cnt);
    rescore<<<CAP, 256, 0, stream>>>(queries, affine, keys, cidx, cnt, resc);
    final_select<<<1, 256, 0, stream>>>(cidx, resc, cnt, values, out);
}

// Round 11
// 549.339 us; speedup vs baseline: 2.3526x; 2.3526x over previous
//
#include <hip/hip_runtime.h>
#include <cstdint>
#include <cstddef>

// ---------------------------------------------------------------------------
// AffineMultiQueryHardAttentionEncoder
//   scores[m] = max_n ( (q[n]*a) . k[m] ), top-64, softmax, sum w_i * V[idx_i]
// R11:
//   - prep_keys: row-linear coalesced reads -> bf16 -> glds-ready swizzled
//     kstage (128B-line writes). No LDS, no reg pressure.
//   - scores_gemm: BM=128 BK=64, A+B both global_load_lds 1-ahead dbuf,
//     LDS=160KB, acc in AGPRs, ~80 arch VGPRs (no spill by design).
//     A-read fully linear; B (qstage) L2-resident.
//   - select: TWO-LEVEL histogram (coarse >>19, then 8192 fine bins inside
//     the T64 bin) -> vlo = T64_fine - 0.8  -> ~80 candidates (was ~1000:
//     the hidden 200us tail of R3-R10).
//   - exact f32 rescore + final select unchanged (absmax 0.0 pedigree).
// ---------------------------------------------------------------------------

typedef __attribute__((ext_vector_type(8))) short bf16x8;
typedef __attribute__((ext_vector_type(4))) float f32x4;

static constexpr int NQ = 512;
static constexpr int DD = 1024;
static constexpr int MK = 100000;
static constexpr int BM = 128;
static constexpr int KSTEPS = 16;                     // BK=64
static constexpr int MBLK = (MK + BM - 1) / BM;       // 782
static constexpr int CAP = 1024;

// workspace layout (bytes)
static constexpr size_t KSTAGE_OFF   = 0;   // [782][16 ks][128 row][8 slot][16B]
static constexpr size_t KSTAGE_BYTES = (size_t)MBLK * 262144;          // ~205 MB
static constexpr size_t QSTAGE_OFF   = KSTAGE_OFF + KSTAGE_BYTES;      // 1 MiB
static constexpr size_t QSTAGE_BYTES = (size_t)KSTEPS * 8 * NQ * 16;
static constexpr size_t SCORES_OFF   = QSTAGE_OFF + QSTAGE_BYTES;
static constexpr size_t SCORES_BYTES = (size_t)MBLK * BM * 4;
static constexpr size_t CIDX_OFF     = SCORES_OFF + SCORES_BYTES;
static constexpr size_t RESC_OFF     = CIDX_OFF + (size_t)CAP * 4;
static constexpr size_t CNT_OFF      = RESC_OFF + (size_t)CAP * 4;
static constexpr size_t HISTC_OFF    = CNT_OFF + 64;
static constexpr size_t HISTF_OFF    = HISTC_OFF + 8192 * 4;
static constexpr size_t TB_OFF       = HISTF_OFF + 8192 * 4;
static constexpr size_t VLO_OFF      = TB_OFF + 64;

// gemm LDS: A dbuf 2x16KB @0 ; B dbuf 2x64KB @32768 -> exactly 160 KiB
static constexpr int ABASE = 0;
static constexpr int BBASE = 32768;
static constexpr int GEMM_LDS = 32768 + 2 * 65536;    // 163840

static __device__ __forceinline__ unsigned short f32_to_bf16_rne(float f) {
    unsigned int u = __float_as_uint(f);
    unsigned int r = (u + 0x7FFFu + ((u >> 16) & 1u)) >> 16;
    return (unsigned short)r;
}
static __device__ __forceinline__ unsigned int xform(float f) {
    unsigned int u = __float_as_uint(f);
    return u ^ ((unsigned int)((int)u >> 31) | 0x80000000u);
}
static __device__ __forceinline__ float unxform(unsigned int u) {
    unsigned int b = (u & 0x80000000u) ? (u ^ 0x80000000u) : ~u;
    return __uint_as_float(b);
}

typedef __attribute__((address_space(1))) const unsigned int g1u32;
typedef __attribute__((address_space(3))) unsigned int l3u32;
static __device__ __forceinline__ void async16(const void* g, void* l) {
    __builtin_amdgcn_global_load_lds((g1u32*)g, (l3u32*)(uintptr_t)l, 16, 0, 0);
}

// ---------------------------------------------------------------------------
// prep_q: qa = q*a -> bf16 RNE, fragment-major (R8 layout):
//   chunk id = (ks*8 + j)*512 + q   holds  qa[q][ks*64 + (j>>2)*32 + (j&3)*8 ..+7]
// ---------------------------------------------------------------------------
__global__ void prep_q(const float* __restrict__ q, const float* __restrict__ a,
                       unsigned short* __restrict__ qs) {
    int id = blockIdx.x * 256 + threadIdx.x;    // 0..65535
    int qq = id & 511;
    int j  = (id >> 9) & 7;
    int kk = id >> 12;
    int col = kk * 64 + (j >> 2) * 32 + (j & 3) * 8;

    const float* qrow = q + (size_t)qq * DD + col;
    float4 v0 = *(const float4*)(qrow);
    float4 v1 = *(const float4*)(qrow + 4);
    float4 a0 = *(const float4*)(a + col);
    float4 a1 = *(const float4*)(a + col + 4);
    float f[8] = {v0.x * a0.x, v0.y * a0.y, v0.z * a0.z, v0.w * a0.w,
                  v1.x * a1.x, v1.y * a1.y, v1.z * a1.z, v1.w * a1.w};
    bf16x8 o;
#pragma unroll
    for (int t = 0; t < 8; ++t) o[t] = (short)f32_to_bf16_rne(f[t]);
    *(bf16x8*)(qs + (size_t)id * 8) = o;
}

// ---------------------------------------------------------------------------
// prep_keys: keys f32 -> kstage bf16, glds-ready swizzled layout:
//   kstage[mb] + ks*16384 + row*128 + ((c ^ (row&7))<<4)  holds
//   keys[mb*128+row][ks*64 + c*8 .. +7]
// reads: row-linear 32KB/iter coalesced; writes: full 128B lines.
// ---------------------------------------------------------------------------
__launch_bounds__(1024)
__global__ void prep_keys(const float* __restrict__ keys,
                          unsigned short* __restrict__ kst) {
    const int mb = blockIdx.x;
    const int t  = threadIdx.x;
    char* const dst = (char*)kst + (size_t)mb * 262144;
#pragma unroll
    for (int it = 0; it < 16; ++it) {
        const int idx  = it * 1024 + t;      // 0..16383
        const int row  = idx >> 7;           // 0..127
        const int col8 = idx & 127;          // 8-f32 chunk within row
        const int gm   = mb * BM + row;
        bf16x8 o;
        if (gm < MK) {
            const float* src = keys + (size_t)gm * DD + col8 * 8;
            float4 v0 = *(const float4*)(src);
            float4 v1 = *(const float4*)(src + 4);
            o[0] = (short)f32_to_bf16_rne(v0.x);
            o[1] = (short)f32_to_bf16_rne(v0.y);
            o[2] = (short)f32_to_bf16_rne(v0.z);
            o[3] = (short)f32_to_bf16_rne(v0.w);
            o[4] = (short)f32_to_bf16_rne(v1.x);
            o[5] = (short)f32_to_bf16_rne(v1.y);
            o[6] = (short)f32_to_bf16_rne(v1.z);
            o[7] = (short)f32_to_bf16_rne(v1.w);
        } else {
#pragma unroll
            for (int k = 0; k < 8; ++k) o[k] = 0;
        }
        const int ks = col8 >> 3;
        const int c  = col8 & 7;
        *(bf16x8*)(dst + ks * 16384 + row * 128 + ((c ^ (row & 7)) << 4)) = o;
    }
}

// ---------------------------------------------------------------------------
// prescreen GEMM + column max: A+B via global_load_lds, 1-ahead dbuf
// ---------------------------------------------------------------------------
__launch_bounds__(512)
__global__ void scores_gemm(const unsigned short* __restrict__ kstage,
                            const unsigned short* __restrict__ qs,
                            float* __restrict__ scores) {
    extern __shared__ char smem[];
    const int tid = threadIdx.x;
    const int w   = tid >> 6;
    const int l   = tid & 63;
    const int g   = l >> 4;
    const int r16 = l & 15;

    // bijective XCD swizzle (m204): nwg = 782 = 8*97+6
    const int nwg = gridDim.x;
    const int qq8 = nwg >> 3, rr8 = nwg & 7;
    const int xcd = blockIdx.x & 7, loc = blockIdx.x >> 3;
    const int mb  = (xcd < rr8 ? xcd * (qq8 + 1) : rr8 * (qq8 + 1) + (xcd - rr8) * qq8) + loc;
    const int m0  = mb * BM;

    // staging sources (per-lane; glds adds lane*16 on the LDS side)
    const char* asrc = (const char*)kstage + (size_t)mb * 262144 + w * 2048 + l * 16;
    const char* bsrc = (const char*)qs + (size_t)(w * 64 + l) * 16;

    f32x4 acc[8][4] = {};

    // prologue: stage t=0 into buf0
#pragma unroll
    for (int i = 0; i < 2; ++i)
        async16(asrc + i * 1024, smem + ABASE + w * 2048 + i * 1024);
#pragma unroll
    for (int j = 0; j < 8; ++j)
        async16(bsrc + (size_t)j * 8192, smem + BBASE + j * 8192 + w * 1024);
    __syncthreads();

    for (int t = 0; t < KSTEPS; ++t) {
        const int cur = t & 1, nxt = cur ^ 1;
        if (t + 1 < KSTEPS) {
#pragma unroll
            for (int i = 0; i < 2; ++i)
                async16(asrc + (size_t)(t + 1) * 16384 + i * 1024,
                        smem + ABASE + nxt * 16384 + w * 2048 + i * 1024);
#pragma unroll
            for (int j = 0; j < 8; ++j)
                async16(bsrc + ((size_t)(t + 1) * 8 + j) * 8192,
                        smem + BBASE + nxt * 65536 + j * 8192 + w * 1024);
        }
#pragma unroll
        for (int s = 0; s < 2; ++s) {
            const int c = s * 4 + g;
            bf16x8 af[8], bfr[4];
#pragma unroll
            for (int rt = 0; rt < 8; ++rt)
                af[rt] = *(const bf16x8*)(smem + ABASE + cur * 16384 +
                    (rt * 16 + r16) * 128 + ((c ^ (r16 & 7)) << 4));
#pragma unroll
            for (int ct = 0; ct < 4; ++ct)
                bfr[ct] = *(const bf16x8*)(smem + BBASE + cur * 65536 +
                    c * 8192 + (w * 64 + ct * 16 + r16) * 16);
            __builtin_amdgcn_s_setprio(1);
#pragma unroll
            for (int rt = 0; rt < 8; ++rt)
#pragma unroll
                for (int ct = 0; ct < 4; ++ct)
                    acc[rt][ct] = __builtin_amdgcn_mfma_f32_16x16x32_bf16(
                        af[rt], bfr[ct], acc[rt][ct], 0, 0, 0);
            __builtin_amdgcn_s_setprio(0);
        }
        __syncthreads();
    }

    // epilogue: key = rt*16 + g*4 + r ; q = w*64 + ct*16 + r16
    float* wmax = (float*)smem;   // [8 w][128 keys], overlays A (post-barrier)
#pragma unroll
    for (int rt = 0; rt < 8; ++rt) {
#pragma unroll
        for (int r = 0; r < 4; ++r) {
            float mx = acc[rt][0][r];
            mx = fmaxf(mx, acc[rt][1][r]);
            mx = fmaxf(mx, acc[rt][2][r]);
            mx = fmaxf(mx, acc[rt][3][r]);
#pragma unroll
            for (int off = 1; off < 16; off <<= 1)
                mx = fmaxf(mx, __shfl_xor(mx, off));
            if (r16 == 0) wmax[w * 128 + rt * 16 + g * 4 + r] = mx;
        }
    }
    __syncthreads();
    if (tid < BM) {
        float mx = wmax[tid];
#pragma unroll
        for (int ww = 1; ww < 8; ++ww) mx = fmaxf(mx, wmax[ww * 128 + tid]);
        int gm = m0 + tid;
        if (gm < MK) scores[gm] = mx;
    }
}

// ---------------------------------------------------------------------------
// two-level threshold select
// ---------------------------------------------------------------------------
__global__ void zero_sel(unsigned int* __restrict__ hc, unsigned int* __restrict__ hf,
                         int* __restrict__ cnt) {
    int i = blockIdx.x * 1024 + threadIdx.x;
    if (i < 8192) { hc[i] = 0; hf[i] = 0; }
    if (i == 0) cnt[0] = 0;
}

__global__ void hist_build(const float* __restrict__ scores, unsigned int* __restrict__ hist) {
    __shared__ unsigned int lh[8192];
    for (int i = threadIdx.x; i < 8192; i += 256) lh[i] = 0;
    __syncthreads();
    for (int i = blockIdx.x * 256 + threadIdx.x; i < MK; i += gridDim.x * 256)
        atomicAdd(&lh[xform(scores[i]) >> 19], 1u);
    __syncthreads();
    for (int i = threadIdx.x; i < 8192; i += 256) {
        unsigned int c = lh[i];
        if (c) atomicAdd(&hist[i], c);
    }
}

__launch_bounds__(1024)
__global__ void find_coarse(const unsigned int* __restrict__ hist, int* __restrict__ tb) {
    __shared__ unsigned int s0[1024], s1[1024];
    const int tid = threadIdx.x;
    unsigned int s = 0;
#pragma unroll
    for (int j = 0; j < 8; ++j) s += hist[tid * 8 + j];
    s0[tid] = s;
    __syncthreads();
    unsigned int* src = s0;
    unsigned int* dst = s1;
    for (int off = 1; off < 1024; off <<= 1) {
        unsigned int v = src[tid] + ((tid + off < 1024) ? src[tid + off] : 0u);
        __syncthreads();
        dst[tid] = v;
        __syncthreads();
        unsigned int* t = src; src = dst; dst = t;
    }
    unsigned int suf  = src[tid];
    unsigned int sufn = (tid < 1023) ? src[tid + 1] : 0u;
    if (suf >= 64u && sufn < 64u) {
        unsigned int acc = sufn, hb = 0;
        int b = tid * 8 + 7;
        for (;; --b) { hb = hist[b]; acc += hb; if (acc >= 64u) break; }
        tb[0] = b;
        tb[1] = (int)(acc - hb);   // count strictly above coarse bin b
    }
}

__global__ void hist_fine(const float* __restrict__ scores, const int* __restrict__ tb,
                          unsigned int* __restrict__ fh) {
    __shared__ unsigned int lh[8192];
    for (int i = threadIdx.x; i < 8192; i += 256) lh[i] = 0;
    __syncthreads();
    const unsigned int b = (unsigned int)tb[0];
    for (int i = blockIdx.x * 256 + threadIdx.x; i < MK; i += gridDim.x * 256) {
        unsigned int u = xform(scores[i]);
        if ((u >> 19) == b) atomicAdd(&lh[(u >> 6) & 8191u], 1u);
    }
    __syncthreads();
    for (int i = threadIdx.x; i < 8192; i += 256) {
        unsigned int c = lh[i];
        if (c) atomicAdd(&fh[i], c);
    }
}

__launch_bounds__(1024)
__global__ void find_fine(const unsigned int* __restrict__ fh, const int* __restrict__ tb,
                          float* __restrict__ vlo) {
    __shared__ unsigned int s0[1024], s1[1024];
    const int tid = threadIdx.x;
    const unsigned int init = (unsigned int)tb[1];
    unsigned int s = 0;
#pragma unroll
    for (int j = 0; j < 8; ++j) s += fh[tid * 8 + j];
    s0[tid] = s;
    __syncthreads();
    unsigned int* src = s0;
    unsigned int* dst = s1;
    for (int off = 1; off < 1024; off <<= 1) {
        unsigned int v = src[tid] + ((tid + off < 1024) ? src[tid + off] : 0u);
        __syncthreads();
        dst[tid] = v;
        __syncthreads();
        unsigned int* t = src; src = dst; dst = t;
    }
    unsigned int suf  = init + src[tid];
    unsigned int sufn = init + ((tid < 1023) ? src[tid + 1] : 0u);
    if (suf >= 64u && sufn < 64u) {
        unsigned int acc = sufn;
        int b = tid * 8 + 7;
        for (;; --b) { acc += fh[b]; if (acc >= 64u) break; }
        vlo[0] = unxform(((unsigned int)tb[0] << 19) | ((unsigned int)b << 6)) - 0.8f;
    }
}

__global__ void collect(const float* __restrict__ scores, const float* __restrict__ vlo,
                        int* __restrict__ cidx, int* __restrict__ cnt) {
    const float t = vlo[0];
    for (int i = blockIdx.x * 256 + threadIdx.x; i < MK; i += gridDim.x * 256) {
        if (scores[i] >= t) {
            int p = atomicAdd(cnt, 1);
            if (p < CAP) cidx[p] = i;
        }
    }
}

// ---------------------------------------------------------------------------
// exact f32 rescore: one block per candidate, max over 512 queries
// ---------------------------------------------------------------------------
__launch_bounds__(256)
__global__ void rescore(const float* __restrict__ q, const float* __restrict__ a,
                        const float* __restrict__ keys,
                        const int* __restrict__ cidx, const int* __restrict__ cnt,
                        float* __restrict__ resc) {
    __shared__ float wsm[1024];
    __shared__ float smax[4];
    const int b = blockIdx.x;
    if (b >= cnt[0]) return;
    const int m   = cidx[b];
    const int tid = threadIdx.x;

    for (int d = tid; d < 1024; d += 256) wsm[d] = a[d] * keys[(size_t)m * DD + d];
    __syncthreads();

    const int wid = tid >> 6, lane = tid & 63;
    float best = -__builtin_inff();
    for (int n = wid; n < NQ; n += 4) {
        const float* qr = q + (size_t)n * DD;
        float p = 0.f;
#pragma unroll
        for (int j = 0; j < 4; ++j) {
            float4 v  = *(const float4*)(qr + lane * 4 + 256 * j);
            float4 ww = *(const float4*)(&wsm[lane * 4 + 256 * j]);
            p += v.x * ww.x + v.y * ww.y + v.z * ww.z + v.w * ww.w;
        }
#pragma unroll
        for (int off = 1; off < 64; off <<= 1) p += __shfl_xor(p, off);
        best = fmaxf(best, p);
    }
    if (lane == 0) smax[wid] = best;
    __syncthreads();
    if (tid == 0)
        resc[b] = fmaxf(fmaxf(smax[0], smax[1]), fmaxf(smax[2], smax[3]));
}

// ---------------------------------------------------------------------------
// final: top-64 over candidates (exact vals, tie: idx asc), softmax, gather V
// ---------------------------------------------------------------------------
__launch_bounds__(256)
__global__ void final_select(const int* __restrict__ cidx, const float* __restrict__ resc,
                             const int* __restrict__ cnt, const float* __restrict__ values,
                             float* __restrict__ out) {
    __shared__ float selw[64];
    __shared__ int   seli[64];
    const int tid = threadIdx.x;
    int nc = cnt[0];
    if (nc > CAP) nc = CAP;

    if (tid < 64) {
        const int lane = tid;
        float lv[16]; int li[16];
#pragma unroll
        for (int j = 0; j < 16; ++j) {
            int slot = lane + 64 * j;
            bool ok = slot < nc;
            lv[j] = ok ? resc[slot] : -__builtin_inff();
            li[j] = ok ? cidx[slot] : 0x7fffffff;
        }
        for (int it = 0; it < 64; ++it) {
            float bv = -__builtin_inff();
            int bg = 0x7fffffff, bj = 0;
#pragma unroll
            for (int j = 0; j < 16; ++j)
                if (lv[j] > bv || (lv[j] == bv && li[j] < bg)) { bv = lv[j]; bg = li[j]; bj = j; }
            int bcode = (lane << 4) | bj;
#pragma unroll
            for (int off = 1; off < 64; off <<= 1) {
                float ov = __shfl_xor(bv, off);
                int   og = __shfl_xor(bg, off);
                int   oc = __shfl_xor(bcode, off);
                if (ov > bv || (ov == bv && og < bg)) { bv = ov; bg = og; bcode = oc; }
            }
            if ((bcode >> 4) == lane) {
                int wj = bcode & 15;
#pragma unroll
                for (int j = 0; j < 16; ++j) if (j == wj) lv[j] = -__builtin_inff();
            }
            if (lane == 0) { selw[it] = bv; seli[it] = bg; }
        }
    }
    __syncthreads();

    if (tid < 64) {
        float x = selw[tid];
        float mx = x;
#pragma unroll
        for (int off = 1; off < 64; off <<= 1) mx = fmaxf(mx, __shfl_xor(mx, off));
        float e = expf(x - mx);
        float s = e;
#pragma unroll
        for (int off = 1; off < 64; off <<= 1) s += __shfl_xor(s, off);
        selw[tid] = e / s;
        out[DD + tid] = (float)seli[tid];
    }
    __syncthreads();

    for (int d = tid; d < DD; d += 256) {
        float accv = 0.f;
        for (int i = 0; i < 64; ++i)
            accv += selw[i] * values[(size_t)seli[i] * DD + d];
        out[d] = accv;
    }
}

// ---------------------------------------------------------------------------
extern "C" void kernel_launch(void* const* d_in, const int* in_sizes, int n_in,
                              void* d_out, int out_size, void* d_ws, size_t ws_size,
                              hipStream_t stream) {
    (void)in_sizes; (void)n_in; (void)out_size; (void)ws_size;
    const float* queries = (const float*)d_in[0];
    const float* keys    = (const float*)d_in[1];
    const float* values  = (const float*)d_in[2];
    const float* affine  = (const float*)d_in[3];
    float* out = (float*)d_out;
    char*  ws  = (char*)d_ws;

    unsigned short* kstage = (unsigned short*)(ws + KSTAGE_OFF);
    unsigned short* qstage = (unsigned short*)(ws + QSTAGE_OFF);
    float* scores = (float*)(ws + SCORES_OFF);
    int*   cidx   = (int*)(ws + CIDX_OFF);
    float* resc   = (float*)(ws + RESC_OFF);
    int*   cnt    = (int*)(ws + CNT_OFF);
    unsigned int* hc = (unsigned int*)(ws + HISTC_OFF);
    unsigned int* hf = (unsigned int*)(ws + HISTF_OFF);
    int*   tb     = (int*)(ws + TB_OFF);
    float* vlo    = (float*)(ws + VLO_OFF);

    hipFuncSetAttribute((const void*)scores_gemm,
                        hipFuncAttributeMaxDynamicSharedMemorySize, GEMM_LDS);

    prep_q<<<256, 256, 0, stream>>>(queries, affine, qstage);
    prep_keys<<<MBLK, 1024, 0, stream>>>(keys, kstage);
    scores_gemm<<<MBLK, 512, GEMM_LDS, stream>>>(kstage, qstage, scores);
    zero_sel<<<8, 1024, 0, stream>>>(hc, hf, cnt);
    hist_build<<<64, 256, 0, stream>>>(scores, hc);
    find_coarse<<<1, 1024, 0, stream>>>(hc, tb);
    hist_fine<<<64, 256, 0, stream>>>(scores, tb, hf);
    find_fine<<<1, 1024, 0, stream>>>(hf, tb, vlo);
    collect<<<200, 256, 0, stream>>>(scores, vlo, cidx, cnt);
    rescore<<<CAP, 256, 0, stream>>>(queries, affine, keys, cidx, cnt, resc);
    final_select<<<1, 256, 0, stream>>>(cidx, resc, cnt, values, out);
}

// Round 12
// 442.191 us; speedup vs baseline: 2.9227x; 1.2423x over previous
//
#include <hip/hip_runtime.h>
#include <cstdint>
#include <cstddef>

// ---------------------------------------------------------------------------
// AffineMultiQueryHardAttentionEncoder
//   scores[m] = max_n ( (q[n]*a) . k[m] ), top-64, softmax, sum w_i * V[idx_i]
// R12 = R8 (best @445us) + two changes:
//   (1) A-load geometry: 16 lanes per row -> each wave-instr reads
//       4 rows x 256B contiguous (R8: 16 rows x 64B). Same regs, same
//       vmcnt(4) pipeline, same LDS layout (A-writes become 4x b64).
//   (2) two-level histogram tail (R11, verified): fine threshold ->
//       ~80 candidates instead of ~1000 -> rescore 10x cheaper.
// ---------------------------------------------------------------------------

typedef __attribute__((ext_vector_type(8))) short bf16x8;
typedef __attribute__((ext_vector_type(4))) float f32x4;

static constexpr int NQ = 512;
static constexpr int DD = 1024;
static constexpr int MK = 100000;
static constexpr int BM = 128;
static constexpr int KSTEPS = DD / 64;                 // 16 (BK=64)
static constexpr int MBLK = (MK + BM - 1) / BM;        // 782
static constexpr int CAP = 1024;

// workspace layout (bytes)
static constexpr size_t QSTAGE_OFF   = 0;    // [16 kk][2 s][4 g][512 q][16B] = 1 MiB
static constexpr size_t QSTAGE_BYTES = (size_t)KSTEPS * 8 * NQ * 16;
static constexpr size_t SCORES_OFF   = QSTAGE_OFF + QSTAGE_BYTES;
static constexpr size_t SCORES_BYTES = (size_t)MBLK * BM * 4;
static constexpr size_t CIDX_OFF     = SCORES_OFF + SCORES_BYTES;
static constexpr size_t RESC_OFF     = CIDX_OFF + (size_t)CAP * 4;
static constexpr size_t CNT_OFF      = RESC_OFF + (size_t)CAP * 4;
static constexpr size_t HISTC_OFF    = CNT_OFF + 64;
static constexpr size_t HISTF_OFF    = HISTC_OFF + 8192 * 4;
static constexpr size_t TB_OFF       = HISTF_OFF + 8192 * 4;
static constexpr size_t VLO_OFF      = TB_OFF + 64;

// gemm LDS: A dbuf 2 x [8 chunk][128 row][16B]=16KB @0 ; B dbuf 2x64KB @32768
static constexpr int ABASE = 0;
static constexpr int BBASE = 32768;
static constexpr int GEMM_LDS = 32768 + 2 * 65536;     // 163840 = 160 KiB

static __device__ __forceinline__ unsigned short f32_to_bf16_rne(float f) {
    unsigned int u = __float_as_uint(f);
    unsigned int r = (u + 0x7FFFu + ((u >> 16) & 1u)) >> 16;
    return (unsigned short)r;
}
static __device__ __forceinline__ unsigned int xform(float f) {
    unsigned int u = __float_as_uint(f);
    return u ^ ((unsigned int)((int)u >> 31) | 0x80000000u);
}
static __device__ __forceinline__ float unxform(unsigned int u) {
    unsigned int b = (u & 0x80000000u) ? (u ^ 0x80000000u) : ~u;
    return __uint_as_float(b);
}

typedef __attribute__((address_space(1))) const unsigned int g1u32;
typedef __attribute__((address_space(3))) unsigned int l3u32;
static __device__ __forceinline__ void async16(const void* g, void* l) {
    __builtin_amdgcn_global_load_lds((g1u32*)g, (l3u32*)(uintptr_t)l, 16, 0, 0);
}

// ---------------------------------------------------------------------------
// prep_q: qa = q*a -> bf16 RNE in fragment-major order (R8 layout):
//   chunk id = ((kk*2+s)*4+g)*512 + q  holds  qa[q][kk*64+s*32+g*8 .. +7]
// ---------------------------------------------------------------------------
__global__ void prep_q(const float* __restrict__ q, const float* __restrict__ a,
                       unsigned short* __restrict__ qs) {
    int id = blockIdx.x * 256 + threadIdx.x;    // 0..65535
    int qq = id & 511;
    int j  = (id >> 9) & 7;                     // s*4+g
    int kk = id >> 12;
    int col = kk * 64 + (j >> 2) * 32 + (j & 3) * 8;

    const float* qrow = q + (size_t)qq * DD + col;
    float4 v0 = *(const float4*)(qrow);
    float4 v1 = *(const float4*)(qrow + 4);
    float4 a0 = *(const float4*)(a + col);
    float4 a1 = *(const float4*)(a + col + 4);
    float f[8] = {v0.x * a0.x, v0.y * a0.y, v0.z * a0.z, v0.w * a0.w,
                  v1.x * a1.x, v1.y * a1.y, v1.z * a1.z, v1.w * a1.w};
    bf16x8 o;
#pragma unroll
    for (int t = 0; t < 8; ++t) o[t] = (short)f32_to_bf16_rne(f[t]);
    *(bf16x8*)(qs + (size_t)id * 8) = o;
}

// ---------------------------------------------------------------------------
// prescreen GEMM + column max, counted-vmcnt pipeline (R8 core)
// ---------------------------------------------------------------------------
__launch_bounds__(512, 2)
__global__ void scores_gemm(const float* __restrict__ keys,
                            const unsigned short* __restrict__ qs,
                            float* __restrict__ scores) {
    extern __shared__ char smem[];
    const int tid  = threadIdx.x;
    const int wid  = tid >> 6;
    const int lane = tid & 63;
    const int g    = lane >> 4;
    const int r16  = lane & 15;
    const int wq   = wid & 3;     // query quarter (128 q)
    const int wk   = wid >> 2;    // key half (64 keys)

    // bijective XCD swizzle (m204); nwg = 782 = 8*97+6
    const int nwg = gridDim.x;
    const int qq8 = nwg >> 3, rr8 = nwg & 7;
    const int xcd = blockIdx.x & 7, loc = blockIdx.x >> 3;
    const int mb  = (xcd < rr8 ? xcd * (qq8 + 1) : rr8 * (qq8 + 1) + (xcd - rr8) * qq8) + loc;
    const int m0  = mb * BM;

    // ---- A staging geometry (NEW): load i covers rows i*32 + wid*4 + (lane>>4),
    // cols (lane&15)*4 .. +3 of the 64-col K-slice. Per wave-instr: 4 rows x
    // 256B contiguous (R8 was 16 rows x 64B).
    const int c0 = (lane & 15) * 4;            // f32 col within K-slice
    const float* rowp[4];
    int awb[4];                                 // LDS byte offset per load
#pragma unroll
    for (int i = 0; i < 4; ++i) {
        int rl = i * 32 + wid * 4 + (lane >> 4);
        int gr = m0 + rl; if (gr > MK - 1) gr = MK - 1;
        rowp[i] = keys + (size_t)gr * DD + c0;
        // LDS layout [chunk=c0>>3][row][16B], half = (c0>>2)&1
        awb[i] = (c0 >> 3) * 2048 + rl * 16 + (c0 & 4) * 2;
    }

    // ---- B staging: wave stages q in [64*wid, +64) for all 8 (s,g) chunks
    const char* qsrc = (const char*)qs + (size_t)(64 * wid + lane) * 16;
    const int   bw0  = (64 * wid) * 16;    // + BBASE + buf*65536 + j*8192

    f32x4 acc[4][8] = {};
    float4 P[4], Q[4];

#define STAGE_B(T1, BUF) do {                                                  \
    _Pragma("unroll")                                                          \
    for (int j = 0; j < 8; ++j)                                                \
        async16(qsrc + ((size_t)(T1) * 8 + j) * 8192,                          \
                smem + BBASE + (BUF) * 65536 + j * 8192 + bw0);                \
} while (0)

#define LOAD_A(TT, R) do {                                                     \
    int tA_ = (TT) < 15 ? (TT) : 15;                                           \
    _Pragma("unroll")                                                          \
    for (int i = 0; i < 4; ++i)                                                \
        R[i] = *(const float4*)(rowp[i] + tA_ * 64);                           \
} while (0)

#define WRITE_A(R, BUF) do {                                                   \
    _Pragma("unroll")                                                          \
    for (int i = 0; i < 4; ++i) {                                              \
        unsigned long long pk_ =                                               \
            (unsigned long long)f32_to_bf16_rne(R[i].x)                        \
          | ((unsigned long long)f32_to_bf16_rne(R[i].y) << 16)                \
          | ((unsigned long long)f32_to_bf16_rne(R[i].z) << 32)                \
          | ((unsigned long long)f32_to_bf16_rne(R[i].w) << 48);               \
        *(unsigned long long*)(smem + ABASE + (BUF) * 16384 + awb[i]) = pk_;   \
    }                                                                          \
} while (0)

#define COMPUTE(BUF) do {                                                      \
    _Pragma("unroll")                                                          \
    for (int s = 0; s < 2; ++s) {                                              \
        bf16x8 af[4], bf[8];                                                   \
        _Pragma("unroll")                                                      \
        for (int rt = 0; rt < 4; ++rt)                                         \
            af[rt] = *(const bf16x8*)(smem + ABASE + (BUF) * 16384 +           \
                ((s * 4 + g) * 128 + wk * 64 + rt * 16 + r16) * 16);           \
        _Pragma("unroll")                                                      \
        for (int ct = 0; ct < 8; ++ct)                                         \
            bf[ct] = *(const bf16x8*)(smem + BBASE + (BUF) * 65536 +           \
                (s * 4 + g) * 8192 + (wq * 128 + ct * 16 + r16) * 16);         \
        __builtin_amdgcn_s_setprio(1);                                         \
        _Pragma("unroll")                                                      \
        for (int rt = 0; rt < 4; ++rt)                                         \
            _Pragma("unroll")                                                  \
            for (int ct = 0; ct < 8; ++ct)                                     \
                acc[rt][ct] = __builtin_amdgcn_mfma_f32_16x16x32_bf16(         \
                    af[rt], bf[ct], acc[rt][ct], 0, 0, 0);                     \
        __builtin_amdgcn_s_setprio(0);                                         \
    }                                                                          \
} while (0)

#define PIPE_BARRIER() do {                                                    \
    asm volatile("s_waitcnt vmcnt(4) lgkmcnt(0)" ::: "memory");                \
    __builtin_amdgcn_s_barrier();                                              \
    asm volatile("" ::: "memory");                                             \
} while (0)

// iter t: stage B(t+1)->buf[nxt]; load A(t+2)->RL; compute buf[cur];
//         convert RC (=A(t+1)) -> ds_write buf[nxt]; counted barrier.
#define ITER(T, RC, RL) do {                                                   \
    const int cur_ = (T) & 1, nxt_ = cur_ ^ 1;                                 \
    STAGE_B((T) + 1, nxt_);                                                    \
    asm volatile("" ::: "memory");  /* pin: B-glds issue before A-loads */     \
    LOAD_A((T) + 2, RL);                                                       \
    COMPUTE(cur_);                                                             \
    WRITE_A(RC, nxt_);                                                         \
    PIPE_BARRIER();                                                            \
} while (0)

    // ---- prologue: B(0)+A(0)->buf0, A(1) in flight
    STAGE_B(0, 0);
    asm volatile("" ::: "memory");
    LOAD_A(0, P);
    LOAD_A(1, Q);
    WRITE_A(P, 0);          // compiler waits A(0); B(0) (older) drains too
    PIPE_BARRIER();         // leaves A(1) in flight

    for (int t2 = 0; t2 < 7; ++t2) {
        ITER(2 * t2,     Q, P);
        ITER(2 * t2 + 1, P, Q);
    }
    ITER(14, Q, P);

    // ---- epilogue K-step 15 (buf1), then full drain
    COMPUTE(1);
    __syncthreads();

#undef STAGE_B
#undef LOAD_A
#undef WRITE_A
#undef COMPUTE
#undef PIPE_BARRIER
#undef ITER

    // ---- epilogue: max over queries. acc[rt][ct][r]: key = wk*64+rt*16+g*4+r,
    // query = wq*128 + ct*16 + r16. Reduce over ct then r16, fold wq via LDS.
    float* wmax = (float*)smem;   // [4 wq][128 keys]
#pragma unroll
    for (int rt = 0; rt < 4; ++rt) {
#pragma unroll
        for (int r = 0; r < 4; ++r) {
            float mx = acc[rt][0][r];
#pragma unroll
            for (int ct = 1; ct < 8; ++ct) mx = fmaxf(mx, acc[rt][ct][r]);
#pragma unroll
            for (int off = 1; off < 16; off <<= 1)
                mx = fmaxf(mx, __shfl_xor(mx, off));
            if (r16 == 0) wmax[wq * 128 + wk * 64 + rt * 16 + g * 4 + r] = mx;
        }
    }
    __syncthreads();
    if (tid < BM) {
        float mx = fmaxf(fmaxf(wmax[tid], wmax[128 + tid]),
                         fmaxf(wmax[256 + tid], wmax[384 + tid]));
        int gm = m0 + tid;
        if (gm < MK) scores[gm] = mx;
    }
}

// ---------------------------------------------------------------------------
// two-level threshold select (R11, verified)
// ---------------------------------------------------------------------------
__global__ void zero_sel(unsigned int* __restrict__ hc, unsigned int* __restrict__ hf,
                         int* __restrict__ cnt) {
    int i = blockIdx.x * 1024 + threadIdx.x;
    if (i < 8192) { hc[i] = 0; hf[i] = 0; }
    if (i == 0) cnt[0] = 0;
}

__global__ void hist_build(const float* __restrict__ scores, unsigned int* __restrict__ hist) {
    __shared__ unsigned int lh[8192];
    for (int i = threadIdx.x; i < 8192; i += 256) lh[i] = 0;
    __syncthreads();
    for (int i = blockIdx.x * 256 + threadIdx.x; i < MK; i += gridDim.x * 256)
        atomicAdd(&lh[xform(scores[i]) >> 19], 1u);
    __syncthreads();
    for (int i = threadIdx.x; i < 8192; i += 256) {
        unsigned int c = lh[i];
        if (c) atomicAdd(&hist[i], c);
    }
}

__launch_bounds__(1024)
__global__ void find_coarse(const unsigned int* __restrict__ hist, int* __restrict__ tb) {
    __shared__ unsigned int s0[1024], s1[1024];
    const int tid = threadIdx.x;
    unsigned int s = 0;
#pragma unroll
    for (int j = 0; j < 8; ++j) s += hist[tid * 8 + j];
    s0[tid] = s;
    __syncthreads();
    unsigned int* src = s0;
    unsigned int* dst = s1;
    for (int off = 1; off < 1024; off <<= 1) {
        unsigned int v = src[tid] + ((tid + off < 1024) ? src[tid + off] : 0u);
        __syncthreads();
        dst[tid] = v;
        __syncthreads();
        unsigned int* t = src; src = dst; dst = t;
    }
    unsigned int suf  = src[tid];
    unsigned int sufn = (tid < 1023) ? src[tid + 1] : 0u;
    if (suf >= 64u && sufn < 64u) {
        unsigned int acc = sufn, hb = 0;
        int b = tid * 8 + 7;
        for (;; --b) { hb = hist[b]; acc += hb; if (acc >= 64u) break; }
        tb[0] = b;
        tb[1] = (int)(acc - hb);   // count strictly above coarse bin b
    }
}

__global__ void hist_fine(const float* __restrict__ scores, const int* __restrict__ tb,
                          unsigned int* __restrict__ fh) {
    __shared__ unsigned int lh[8192];
    for (int i = threadIdx.x; i < 8192; i += 256) lh[i] = 0;
    __syncthreads();
    const unsigned int b = (unsigned int)tb[0];
    for (int i = blockIdx.x * 256 + threadIdx.x; i < MK; i += gridDim.x * 256) {
        unsigned int u = xform(scores[i]);
        if ((u >> 19) == b) atomicAdd(&lh[(u >> 6) & 8191u], 1u);
    }
    __syncthreads();
    for (int i = threadIdx.x; i < 8192; i += 256) {
        unsigned int c = lh[i];
        if (c) atomicAdd(&fh[i], c);
    }
}

__launch_bounds__(1024)
__global__ void find_fine(const unsigned int* __restrict__ fh, const int* __restrict__ tb,
                          float* __restrict__ vlo) {
    __shared__ unsigned int s0[1024], s1[1024];
    const int tid = threadIdx.x;
    const unsigned int init = (unsigned int)tb[1];
    unsigned int s = 0;
#pragma unroll
    for (int j = 0; j < 8; ++j) s += fh[tid * 8 + j];
    s0[tid] = s;
    __syncthreads();
    unsigned int* src = s0;
    unsigned int* dst = s1;
    for (int off = 1; off < 1024; off <<= 1) {
        unsigned int v = src[tid] + ((tid + off < 1024) ? src[tid + off] : 0u);
        __syncthreads();
        dst[tid] = v;
        __syncthreads();
        unsigned int* t = src; src = dst; dst = t;
    }
    unsigned int suf  = init + src[tid];
    unsigned int sufn = init + ((tid < 1023) ? src[tid + 1] : 0u);
    if (suf >= 64u && sufn < 64u) {
        unsigned int acc = sufn;
        int b = tid * 8 + 7;
        for (;; --b) { acc += fh[b]; if (acc >= 64u) break; }
        vlo[0] = unxform(((unsigned int)tb[0] << 19) | ((unsigned int)b << 6)) - 0.8f;
    }
}

__global__ void collect(const float* __restrict__ scores, const float* __restrict__ vlo,
                        int* __restrict__ cidx, int* __restrict__ cnt) {
    const float t = vlo[0];
    for (int i = blockIdx.x * 256 + threadIdx.x; i < MK; i += gridDim.x * 256) {
        if (scores[i] >= t) {
            int p = atomicAdd(cnt, 1);
            if (p < CAP) cidx[p] = i;
        }
    }
}

// ---------------------------------------------------------------------------
// exact f32 rescore: one block per candidate, max over 512 queries
// ---------------------------------------------------------------------------
__launch_bounds__(256)
__global__ void rescore(const float* __restrict__ q, const float* __restrict__ a,
                        const float* __restrict__ keys,
                        const int* __restrict__ cidx, const int* __restrict__ cnt,
                        float* __restrict__ resc) {
    __shared__ float wsm[1024];
    __shared__ float smax[4];
    const int b = blockIdx.x;
    if (b >= cnt[0]) return;
    const int m   = cidx[b];
    const int tid = threadIdx.x;

    for (int d = tid; d < 1024; d += 256) wsm[d] = a[d] * keys[(size_t)m * DD + d];
    __syncthreads();

    const int wid = tid >> 6, lane = tid & 63;
    float best = -__builtin_inff();
    for (int n = wid; n < NQ; n += 4) {
        const float* qr = q + (size_t)n * DD;
        float p = 0.f;
#pragma unroll
        for (int j = 0; j < 4; ++j) {
            float4 v  = *(const float4*)(qr + lane * 4 + 256 * j);
            float4 ww = *(const float4*)(&wsm[lane * 4 + 256 * j]);
            p += v.x * ww.x + v.y * ww.y + v.z * ww.z + v.w * ww.w;
        }
#pragma unroll
        for (int off = 1; off < 64; off <<= 1) p += __shfl_xor(p, off);
        best = fmaxf(best, p);
    }
    if (lane == 0) smax[wid] = best;
    __syncthreads();
    if (tid == 0)
        resc[b] = fmaxf(fmaxf(smax[0], smax[1]), fmaxf(smax[2], smax[3]));
}

// ---------------------------------------------------------------------------
// final: top-64 over candidates (exact vals, tie: idx asc), softmax, gather V
// ---------------------------------------------------------------------------
__launch_bounds__(256)
__global__ void final_select(const int* __restrict__ cidx, const float* __restrict__ resc,
                             const int* __restrict__ cnt, const float* __restrict__ values,
                             float* __restrict__ out) {
    __shared__ float selw[64];
    __shared__ int   seli[64];
    const int tid = threadIdx.x;
    int nc = cnt[0];
    if (nc > CAP) nc = CAP;

    if (tid < 64) {
        const int lane = tid;
        float lv[16]; int li[16];
#pragma unroll
        for (int j = 0; j < 16; ++j) {
            int slot = lane + 64 * j;
            bool ok = slot < nc;
            lv[j] = ok ? resc[slot] : -__builtin_inff();
            li[j] = ok ? cidx[slot] : 0x7fffffff;
        }
        for (int it = 0; it < 64; ++it) {
            float bv = -__builtin_inff();
            int bg = 0x7fffffff, bj = 0;
#pragma unroll
            for (int j = 0; j < 16; ++j)
                if (lv[j] > bv || (lv[j] == bv && li[j] < bg)) { bv = lv[j]; bg = li[j]; bj = j; }
            int bcode = (lane << 4) | bj;
#pragma unroll
            for (int off = 1; off < 64; off <<= 1) {
                float ov = __shfl_xor(bv, off);
                int   og = __shfl_xor(bg, off);
                int   oc = __shfl_xor(bcode, off);
                if (ov > bv || (ov == bv && og < bg)) { bv = ov; bg = og; bcode = oc; }
            }
            if ((bcode >> 4) == lane) {
                int wj = bcode & 15;
#pragma unroll
                for (int j = 0; j < 16; ++j) if (j == wj) lv[j] = -__builtin_inff();
            }
            if (lane == 0) { selw[it] = bv; seli[it] = bg; }
        }
    }
    __syncthreads();

    if (tid < 64) {
        float x = selw[tid];
        float mx = x;
#pragma unroll
        for (int off = 1; off < 64; off <<= 1) mx = fmaxf(mx, __shfl_xor(mx, off));
        float e = expf(x - mx);
        float s = e;
#pragma unroll
        for (int off = 1; off < 64; off <<= 1) s += __shfl_xor(s, off);
        selw[tid] = e / s;
        out[DD + tid] = (float)seli[tid];
    }
    __syncthreads();

    for (int d = tid; d < DD; d += 256) {
        float accv = 0.f;
        for (int i = 0; i < 64; ++i)
            accv += selw[i] * values[(size_t)seli[i] * DD + d];
        out[d] = accv;
    }
}

// ---------------------------------------------------------------------------
extern "C" void kernel_launch(void* const* d_in, const int* in_sizes, int n_in,
                              void* d_out, int out_size, void* d_ws, size_t ws_size,
                              hipStream_t stream) {
    (void)in_sizes; (void)n_in; (void)out_size; (void)ws_size;
    const float* queries = (const float*)d_in[0];
    const float* keys    = (const float*)d_in[1];
    const float* values  = (const float*)d_in[2];
    const float* affine  = (const float*)d_in[3];
    float* out = (float*)d_out;
    char*  ws  = (char*)d_ws;

    unsigned short* qstage = (unsigned short*)(ws + QSTAGE_OFF);
    float* scores = (float*)(ws + SCORES_OFF);
    int*   cidx   = (int*)(ws + CIDX_OFF);
    float* resc   = (float*)(ws + RESC_OFF);
    int*   cnt    = (int*)(ws + CNT_OFF);
    unsigned int* hc = (unsigned int*)(ws + HISTC_OFF);
    unsigned int* hf = (unsigned int*)(ws + HISTF_OFF);
    int*   tb     = (int*)(ws + TB_OFF);
    float* vlo    = (float*)(ws + VLO_OFF);

    hipFuncSetAttribute((const void*)scores_gemm,
                        hipFuncAttributeMaxDynamicSharedMemorySize, GEMM_LDS);

    prep_q<<<256, 256, 0, stream>>>(queries, affine, qstage);
    scores_gemm<<<MBLK, 512, GEMM_LDS, stream>>>(keys, qstage, scores);
    zero_sel<<<8, 1024, 0, stream>>>(hc, hf, cnt);
    hist_build<<<64, 256, 0, stream>>>(scores, hc);
    find_coarse<<<1, 1024, 0, stream>>>(hc, tb);
    hist_fine<<<64, 256, 0, stream>>>(scores, tb, hf);
    find_fine<<<1, 1024, 0, stream>>>(hf, tb, vlo);
    collect<<<200, 256, 0, stream>>>(scores, vlo, cidx, cnt);
    rescore<<<CAP, 256, 0, stream>>>(queries, affine, keys, cidx, cnt, resc);
    final_select<<<1, 256, 0, stream>>>(cidx, resc, cnt, values, out);
}

// Round 14
// 431.448 us; speedup vs baseline: 2.9955x; 1.0249x over previous
//
#include <hip/hip_runtime.h>
#include <cstdint>
#include <cstddef>

// ---------------------------------------------------------------------------
// AffineMultiQueryHardAttentionEncoder
//   scores[m] = max_n ( (q[n]*a) . k[m] ), top-64, softmax, sum w_i * V[idx_i]
// R14: R12 skeleton + 3-iteration-lead A pipeline (fixes R12's 34% HBM duty).
//   - BK=32, 32 iters. A(T+4) loaded at iter T (930cy lead), ds_write A(T+1).
//   - B via global_load_lds into ring-3 LDS, staged 2 iters ahead.
//   - barrier vmcnt(8): retires exactly through B(T+1), keeps
//     A(T+3)+B(T+2)+A(T+4) in flight. In-order-safe by issue construction.
//   - LDS 112KB, A-stage regs 32. prep_q + 2-level hist tail: R12 verbatim.
// ---------------------------------------------------------------------------

typedef __attribute__((ext_vector_type(8))) short bf16x8;
typedef __attribute__((ext_vector_type(4))) float f32x4;

static constexpr int NQ = 512;
static constexpr int DD = 1024;
static constexpr int MK = 100000;
static constexpr int BM = 128;
static constexpr int MBLK = (MK + BM - 1) / BM;        // 782
static constexpr int CAP = 1024;

// workspace layout (bytes)
static constexpr size_t QSTAGE_OFF   = 0;    // [32 kks][4 g][512 q][16B] = 1 MiB
static constexpr size_t QSTAGE_BYTES = (size_t)32 * 4 * NQ * 16;
static constexpr size_t SCORES_OFF   = QSTAGE_OFF + QSTAGE_BYTES;
static constexpr size_t SCORES_BYTES = (size_t)MBLK * BM * 4;
static constexpr size_t CIDX_OFF     = SCORES_OFF + SCORES_BYTES;
static constexpr size_t RESC_OFF     = CIDX_OFF + (size_t)CAP * 4;
static constexpr size_t CNT_OFF      = RESC_OFF + (size_t)CAP * 4;
static constexpr size_t HISTC_OFF    = CNT_OFF + 64;
static constexpr size_t HISTF_OFF    = HISTC_OFF + 8192 * 4;
static constexpr size_t TB_OFF       = HISTF_OFF + 8192 * 4;
static constexpr size_t VLO_OFF      = TB_OFF + 64;

// gemm LDS: A dbuf 2 x [4 c16][128 row][16B] = 16KB @0 ; B ring-3 x 32KB @16384
static constexpr int ABASE = 0;
static constexpr int BBASE = 16384;
static constexpr int GEMM_LDS = 16384 + 3 * 32768;     // 114688

static __device__ __forceinline__ unsigned short f32_to_bf16_rne(float f) {
    unsigned int u = __float_as_uint(f);
    unsigned int r = (u + 0x7FFFu + ((u >> 16) & 1u)) >> 16;
    return (unsigned short)r;
}
static __device__ __forceinline__ unsigned int xform(float f) {
    unsigned int u = __float_as_uint(f);
    return u ^ ((unsigned int)((int)u >> 31) | 0x80000000u);
}
static __device__ __forceinline__ float unxform(unsigned int u) {
    unsigned int b = (u & 0x80000000u) ? (u ^ 0x80000000u) : ~u;
    return __uint_as_float(b);
}

typedef __attribute__((address_space(1))) const unsigned int g1u32;
typedef __attribute__((address_space(3))) unsigned int l3u32;
static __device__ __forceinline__ void async16(const void* g, void* l) {
    __builtin_amdgcn_global_load_lds((g1u32*)g, (l3u32*)(uintptr_t)l, 16, 0, 0);
}

// ---------------------------------------------------------------------------
// prep_q (R12 verbatim): chunk id = (kks*4+g)*512 + q holds qa[q][kks*32+g*8..+7]
// ---------------------------------------------------------------------------
__global__ void prep_q(const float* __restrict__ q, const float* __restrict__ a,
                       unsigned short* __restrict__ qs) {
    int id = blockIdx.x * 256 + threadIdx.x;    // 0..65535
    int qq = id & 511;
    int j  = (id >> 9) & 7;
    int kk = id >> 12;
    int col = kk * 64 + (j >> 2) * 32 + (j & 3) * 8;

    const float* qrow = q + (size_t)qq * DD + col;
    float4 v0 = *(const float4*)(qrow);
    float4 v1 = *(const float4*)(qrow + 4);
    float4 a0 = *(const float4*)(a + col);
    float4 a1 = *(const float4*)(a + col + 4);
    float f[8] = {v0.x * a0.x, v0.y * a0.y, v0.z * a0.z, v0.w * a0.w,
                  v1.x * a1.x, v1.y * a1.y, v1.z * a1.z, v1.w * a1.w};
    bf16x8 o;
#pragma unroll
    for (int t = 0; t < 8; ++t) o[t] = (short)f32_to_bf16_rne(f[t]);
    *(bf16x8*)(qs + (size_t)id * 8) = o;
}

// ---------------------------------------------------------------------------
// prescreen GEMM + column max: deep-lead pipeline
// ---------------------------------------------------------------------------
__launch_bounds__(512)
__global__ void scores_gemm(const float* __restrict__ keys,
                            const unsigned short* __restrict__ qs,
                            float* __restrict__ scores) {
    extern __shared__ char smem[];
    const int tid  = threadIdx.x;
    const int wid  = tid >> 6;
    const int lane = tid & 63;
    const int g    = lane >> 4;
    const int r16  = lane & 15;
    const int wq   = wid & 3;     // query quarter (128 q)
    const int wk   = wid >> 2;    // key half (64 keys)

    // bijective XCD swizzle (m204); nwg = 782
    const int nwg = gridDim.x;
    const int qq8 = nwg >> 3, rr8 = nwg & 7;
    const int xcd = blockIdx.x & 7, loc = blockIdx.x >> 3;
    const int mb  = (xcd < rr8 ? xcd * (qq8 + 1) : rr8 * (qq8 + 1) + (xcd - rr8) * qq8) + loc;
    const int m0  = mb * BM;

    // ---- A: wave owns rows wid*16..+16. Per iter (32 f32 cols): 2 loads.
    //   load0: row wid*16 + (lane>>3), f32 col (lane&7)*4 of the step
    //   load1: +8 rows
    const char* kb = (const char*)keys;
    const int rl0 = wid * 16 + (lane >> 3);
    const int rl1 = rl0 + 8;
    int gr0 = m0 + rl0; if (gr0 > MK - 1) gr0 = MK - 1;
    int gr1 = m0 + rl1; if (gr1 > MK - 1) gr1 = MK - 1;
    const size_t aoff0 = (size_t)gr0 * 4096 + (lane & 7) * 16;
    const size_t aoff1 = (size_t)gr1 * 4096 + (lane & 7) * 16;
    const int c16  = (lane & 7) >> 1;
    const int half = (lane & 1) * 8;
    const int awb0 = ((c16 ^ (rl0 & 3)) * 2048) + rl0 * 16 + half;
    const int awb1 = ((c16 ^ (rl1 & 3)) * 2048) + rl1 * 16 + half;

    // ---- B staging: wave stages chunks [wid*256, +256) of each 32KB step
    const char* qsl = (const char*)qs + (size_t)(wid * 256 + lane) * 16;

    f32x4 A0[2], A1[2], A2[2], A3[2];
    f32x4 acc[4][8] = {};

#define STAGE_B(T2, SLOT) do {                                                 \
    _Pragma("unroll")                                                          \
    for (int i = 0; i < 4; ++i)                                                \
        async16(qsl + (size_t)(T2) * 32768 + i * 1024,                         \
                smem + BBASE + (SLOT) * 32768 + wid * 4096 + i * 1024);        \
} while (0)

#define LOAD_A(T4, R) do {                                                     \
    R[0] = *(const f32x4*)(kb + aoff0 + (size_t)(T4) * 128);                   \
    R[1] = *(const f32x4*)(kb + aoff1 + (size_t)(T4) * 128);                   \
} while (0)

#define PK64(V) ( (unsigned long long)f32_to_bf16_rne((V).x)                   \
               | ((unsigned long long)f32_to_bf16_rne((V).y) << 16)            \
               | ((unsigned long long)f32_to_bf16_rne((V).z) << 32)            \
               | ((unsigned long long)f32_to_bf16_rne((V).w) << 48) )

#define WRITE_A(R, SLOT) do {                                                  \
    *(unsigned long long*)(smem + ABASE + (SLOT) * 8192 + awb0) = PK64(R[0]);  \
    *(unsigned long long*)(smem + ABASE + (SLOT) * 8192 + awb1) = PK64(R[1]);  \
} while (0)

#define COMPUTE(T) do {                                                        \
    bf16x8 af[4], bfr[8];                                                      \
    _Pragma("unroll")                                                          \
    for (int rt = 0; rt < 4; ++rt)                                             \
        af[rt] = *(const bf16x8*)(smem + ABASE + ((T) & 1) * 8192 +            \
            ((g ^ (r16 & 3)) * 2048) + (wk * 64 + rt * 16 + r16) * 16);        \
    _Pragma("unroll")                                                          \
    for (int ct = 0; ct < 8; ++ct)                                             \
        bfr[ct] = *(const bf16x8*)(smem + BBASE + ((T) % 3) * 32768 +          \
            g * 8192 + (wq * 128 + ct * 16 + r16) * 16);                       \
    __builtin_amdgcn_s_setprio(1);                                             \
    _Pragma("unroll")                                                          \
    for (int rt = 0; rt < 4; ++rt)                                             \
        _Pragma("unroll")                                                      \
        for (int ct = 0; ct < 8; ++ct)                                         \
            acc[rt][ct] = __builtin_amdgcn_mfma_f32_16x16x32_bf16(             \
                af[rt], bfr[ct], acc[rt][ct], 0, 0, 0);                        \
    __builtin_amdgcn_s_setprio(0);                                             \
} while (0)

#define BARN(N) do {                                                           \
    asm volatile("s_waitcnt vmcnt(" #N ") lgkmcnt(0)" ::: "memory");           \
    __builtin_amdgcn_s_barrier();                                              \
    __builtin_amdgcn_sched_barrier(0);                                         \
} while (0)

// iter T: stage B(T+2), load A(T+4) into BL, compute(T), write A(T+1) from BW
#define ITERF(T, BL, BW) do {                                                  \
    STAGE_B((T) + 2, ((T) + 2) % 3);                                           \
    LOAD_A((T) + 4, BL);                                                       \
    COMPUTE(T);                                                                \
    WRITE_A(BW, ((T) + 1) & 1);                                                \
    BARN(8);                                                                   \
} while (0)

    // ---- prologue: B(0),B(1) staged; A(0..3) in regs; A(0) written
    STAGE_B(0, 0);
    STAGE_B(1, 1);
    LOAD_A(0, A0);
    LOAD_A(1, A1);
    LOAD_A(2, A2);
    LOAD_A(3, A3);
    WRITE_A(A0, 0);          // waits A(0); retires B(0),B(1) (older)
    BARN(6);                 // leaves A(1),A(2),A(3) in flight

    ITERF( 0, A0, A1);  ITERF( 1, A1, A2);  ITERF( 2, A2, A3);  ITERF( 3, A3, A0);
    ITERF( 4, A0, A1);  ITERF( 5, A1, A2);  ITERF( 6, A2, A3);  ITERF( 7, A3, A0);
    ITERF( 8, A0, A1);  ITERF( 9, A1, A2);  ITERF(10, A2, A3);  ITERF(11, A3, A0);
    ITERF(12, A0, A1);  ITERF(13, A1, A2);  ITERF(14, A2, A3);  ITERF(15, A3, A0);
    ITERF(16, A0, A1);  ITERF(17, A1, A2);  ITERF(18, A2, A3);  ITERF(19, A3, A0);
    ITERF(20, A0, A1);  ITERF(21, A1, A2);  ITERF(22, A2, A3);  ITERF(23, A3, A0);
    ITERF(24, A0, A1);  ITERF(25, A1, A2);  ITERF(26, A2, A3);  ITERF(27, A3, A0);

    // T=28: no LOAD_A; stage B(30)
    STAGE_B(30, 0);  COMPUTE(28);  WRITE_A(A1, 1);  BARN(6);
    // T=29: stage B(31)
    STAGE_B(31, 1);  COMPUTE(29);  WRITE_A(A2, 0);  BARN(4);
    // T=30: nothing to stage
    COMPUTE(30);  WRITE_A(A3, 1);  BARN(0);
    // T=31
    COMPUTE(31);
    __syncthreads();

#undef STAGE_B
#undef LOAD_A
#undef PK64
#undef WRITE_A
#undef COMPUTE
#undef BARN
#undef ITERF

    // ---- epilogue: key = wk*64 + rt*16 + g*4 + r ; query = wq*128 + ct*16 + r16
    float* wmax = (float*)smem;   // [4 wq][128 keys]
#pragma unroll
    for (int rt = 0; rt < 4; ++rt) {
#pragma unroll
        for (int r = 0; r < 4; ++r) {
            float mx = acc[rt][0][r];
#pragma unroll
            for (int ct = 1; ct < 8; ++ct) mx = fmaxf(mx, acc[rt][ct][r]);
#pragma unroll
            for (int off = 1; off < 16; off <<= 1)
                mx = fmaxf(mx, __shfl_xor(mx, off));
            if (r16 == 0) wmax[wq * 128 + wk * 64 + rt * 16 + g * 4 + r] = mx;
        }
    }
    __syncthreads();
    if (tid < BM) {
        float mx = fmaxf(fmaxf(wmax[tid], wmax[128 + tid]),
                         fmaxf(wmax[256 + tid], wmax[384 + tid]));
        int gm = m0 + tid;
        if (gm < MK) scores[gm] = mx;
    }
}

// ---------------------------------------------------------------------------
// two-level threshold select (R12 verbatim)
// ---------------------------------------------------------------------------
__global__ void zero_sel(unsigned int* __restrict__ hc, unsigned int* __restrict__ hf,
                         int* __restrict__ cnt) {
    int i = blockIdx.x * 1024 + threadIdx.x;
    if (i < 8192) { hc[i] = 0; hf[i] = 0; }
    if (i == 0) cnt[0] = 0;
}

__global__ void hist_build(const float* __restrict__ scores, unsigned int* __restrict__ hist) {
    __shared__ unsigned int lh[8192];
    for (int i = threadIdx.x; i < 8192; i += 256) lh[i] = 0;
    __syncthreads();
    for (int i = blockIdx.x * 256 + threadIdx.x; i < MK; i += gridDim.x * 256)
        atomicAdd(&lh[xform(scores[i]) >> 19], 1u);
    __syncthreads();
    for (int i = threadIdx.x; i < 8192; i += 256) {
        unsigned int c = lh[i];
        if (c) atomicAdd(&hist[i], c);
    }
}

__launch_bounds__(1024)
__global__ void find_coarse(const unsigned int* __restrict__ hist, int* __restrict__ tb) {
    __shared__ unsigned int s0[1024], s1[1024];
    const int tid = threadIdx.x;
    unsigned int s = 0;
#pragma unroll
    for (int j = 0; j < 8; ++j) s += hist[tid * 8 + j];
    s0[tid] = s;
    __syncthreads();
    unsigned int* src = s0;
    unsigned int* dst = s1;
    for (int off = 1; off < 1024; off <<= 1) {
        unsigned int v = src[tid] + ((tid + off < 1024) ? src[tid + off] : 0u);
        __syncthreads();
        dst[tid] = v;
        __syncthreads();
        unsigned int* t = src; src = dst; dst = t;
    }
    unsigned int suf  = src[tid];
    unsigned int sufn = (tid < 1023) ? src[tid + 1] : 0u;
    if (suf >= 64u && sufn < 64u) {
        unsigned int acc = sufn, hb = 0;
        int b = tid * 8 + 7;
        for (;; --b) { hb = hist[b]; acc += hb; if (acc >= 64u) break; }
        tb[0] = b;
        tb[1] = (int)(acc - hb);   // count strictly above coarse bin b
    }
}

__global__ void hist_fine(const float* __restrict__ scores, const int* __restrict__ tb,
                          unsigned int* __restrict__ fh) {
    __shared__ unsigned int lh[8192];
    for (int i = threadIdx.x; i < 8192; i += 256) lh[i] = 0;
    __syncthreads();
    const unsigned int b = (unsigned int)tb[0];
    for (int i = blockIdx.x * 256 + threadIdx.x; i < MK; i += gridDim.x * 256) {
        unsigned int u = xform(scores[i]);
        if ((u >> 19) == b) atomicAdd(&lh[(u >> 6) & 8191u], 1u);
    }
    __syncthreads();
    for (int i = threadIdx.x; i < 8192; i += 256) {
        unsigned int c = lh[i];
        if (c) atomicAdd(&fh[i], c);
    }
}

__launch_bounds__(1024)
__global__ void find_fine(const unsigned int* __restrict__ fh, const int* __restrict__ tb,
                          float* __restrict__ vlo) {
    __shared__ unsigned int s0[1024], s1[1024];
    const int tid = threadIdx.x;
    const unsigned int init = (unsigned int)tb[1];
    unsigned int s = 0;
#pragma unroll
    for (int j = 0; j < 8; ++j) s += fh[tid * 8 + j];
    s0[tid] = s;
    __syncthreads();
    unsigned int* src = s0;
    unsigned int* dst = s1;
    for (int off = 1; off < 1024; off <<= 1) {
        unsigned int v = src[tid] + ((tid + off < 1024) ? src[tid + off] : 0u);
        __syncthreads();
        dst[tid] = v;
        __syncthreads();
        unsigned int* t = src; src = dst; dst = t;
    }
    unsigned int suf  = init + src[tid];
    unsigned int sufn = init + ((tid < 1023) ? src[tid + 1] : 0u);
    if (suf >= 64u && sufn < 64u) {
        unsigned int acc = sufn;
        int b = tid * 8 + 7;
        for (;; --b) { acc += fh[b]; if (acc >= 64u) break; }
        vlo[0] = unxform(((unsigned int)tb[0] << 19) | ((unsigned int)b << 6)) - 0.8f;
    }
}

__global__ void collect(const float* __restrict__ scores, const float* __restrict__ vlo,
                        int* __restrict__ cidx, int* __restrict__ cnt) {
    const float t = vlo[0];
    for (int i = blockIdx.x * 256 + threadIdx.x; i < MK; i += gridDim.x * 256) {
        if (scores[i] >= t) {
            int p = atomicAdd(cnt, 1);
            if (p < CAP) cidx[p] = i;
        }
    }
}

// ---------------------------------------------------------------------------
// exact f32 rescore: one block per candidate, max over 512 queries
// ---------------------------------------------------------------------------
__launch_bounds__(256)
__global__ void rescore(const float* __restrict__ q, const float* __restrict__ a,
                        const float* __restrict__ keys,
                        const int* __restrict__ cidx, const int* __restrict__ cnt,
                        float* __restrict__ resc) {
    __shared__ float wsm[1024];
    __shared__ float smax[4];
    const int b = blockIdx.x;
    if (b >= cnt[0]) return;
    const int m   = cidx[b];
    const int tid = threadIdx.x;

    for (int d = tid; d < 1024; d += 256) wsm[d] = a[d] * keys[(size_t)m * DD + d];
    __syncthreads();

    const int wid = tid >> 6, lane = tid & 63;
    float best = -__builtin_inff();
    for (int n = wid; n < NQ; n += 4) {
        const float* qr = q + (size_t)n * DD;
        float p = 0.f;
#pragma unroll
        for (int j = 0; j < 4; ++j) {
            float4 v  = *(const float4*)(qr + lane * 4 + 256 * j);
            float4 ww = *(const float4*)(&wsm[lane * 4 + 256 * j]);
            p += v.x * ww.x + v.y * ww.y + v.z * ww.z + v.w * ww.w;
        }
#pragma unroll
        for (int off = 1; off < 64; off <<= 1) p += __shfl_xor(p, off);
        best = fmaxf(best, p);
    }
    if (lane == 0) smax[wid] = best;
    __syncthreads();
    if (tid == 0)
        resc[b] = fmaxf(fmaxf(smax[0], smax[1]), fmaxf(smax[2], smax[3]));
}

// ---------------------------------------------------------------------------
// final: top-64 over candidates (exact vals, tie: idx asc), softmax, gather V
// ---------------------------------------------------------------------------
__launch_bounds__(256)
__global__ void final_select(const int* __restrict__ cidx, const float* __restrict__ resc,
                             const int* __restrict__ cnt, const float* __restrict__ values,
                             float* __restrict__ out) {
    __shared__ float selw[64];
    __shared__ int   seli[64];
    const int tid = threadIdx.x;
    int nc = cnt[0];
    if (nc > CAP) nc = CAP;

    if (tid < 64) {
        const int lane = tid;
        float lv[16]; int li[16];
#pragma unroll
        for (int j = 0; j < 16; ++j) {
            int slot = lane + 64 * j;
            bool ok = slot < nc;
            lv[j] = ok ? resc[slot] : -__builtin_inff();
            li[j] = ok ? cidx[slot] : 0x7fffffff;
        }
        for (int it = 0; it < 64; ++it) {
            float bv = -__builtin_inff();
            int bg = 0x7fffffff, bj = 0;
#pragma unroll
            for (int j = 0; j < 16; ++j)
                if (lv[j] > bv || (lv[j] == bv && li[j] < bg)) { bv = lv[j]; bg = li[j]; bj = j; }
            int bcode = (lane << 4) | bj;
#pragma unroll
            for (int off = 1; off < 64; off <<= 1) {
                float ov = __shfl_xor(bv, off);
                int   og = __shfl_xor(bg, off);
                int   oc = __shfl_xor(bcode, off);
                if (ov > bv || (ov == bv && og < bg)) { bv = ov; bg = og; bcode = oc; }
            }
            if ((bcode >> 4) == lane) {
                int wj = bcode & 15;
#pragma unroll
                for (int j = 0; j < 16; ++j) if (j == wj) lv[j] = -__builtin_inff();
            }
            if (lane == 0) { selw[it] = bv; seli[it] = bg; }
        }
    }
    __syncthreads();

    if (tid < 64) {
        float x = selw[tid];
        float mx = x;
#pragma unroll
        for (int off = 1; off < 64; off <<= 1) mx = fmaxf(mx, __shfl_xor(mx, off));
        float e = expf(x - mx);
        float s = e;
#pragma unroll
        for (int off = 1; off < 64; off <<= 1) s += __shfl_xor(s, off);
        selw[tid] = e / s;
        out[DD + tid] = (float)seli[tid];
    }
    __syncthreads();

    for (int d = tid; d < DD; d += 256) {
        float accv = 0.f;
        for (int i = 0; i < 64; ++i)
            accv += selw[i] * values[(size_t)seli[i] * DD + d];
        out[d] = accv;
    }
}

// ---------------------------------------------------------------------------
extern "C" void kernel_launch(void* const* d_in, const int* in_sizes, int n_in,
                              void* d_out, int out_size, void* d_ws, size_t ws_size,
                              hipStream_t stream) {
    (void)in_sizes; (void)n_in; (void)out_size; (void)ws_size;
    const float* queries = (const float*)d_in[0];
    const float* keys    = (const float*)d_in[1];
    const float* values  = (const float*)d_in[2];
    const float* affine  = (const float*)d_in[3];
    float* out = (float*)d_out;
    char*  ws  = (char*)d_ws;

    unsigned short* qstage = (unsigned short*)(ws + QSTAGE_OFF);
    float* scores = (float*)(ws + SCORES_OFF);
    int*   cidx   = (int*)(ws + CIDX_OFF);
    float* resc   = (float*)(ws + RESC_OFF);
    int*   cnt    = (int*)(ws + CNT_OFF);
    unsigned int* hc = (unsigned int*)(ws + HISTC_OFF);
    unsigned int* hf = (unsigned int*)(ws + HISTF_OFF);
    int*   tb     = (int*)(ws + TB_OFF);
    float* vlo    = (float*)(ws + VLO_OFF);

    hipFuncSetAttribute((const void*)scores_gemm,
                        hipFuncAttributeMaxDynamicSharedMemorySize, GEMM_LDS);

    prep_q<<<256, 256, 0, stream>>>(queries, affine, qstage);
    scores_gemm<<<MBLK, 512, GEMM_LDS, stream>>>(keys, qstage, scores);
    zero_sel<<<8, 1024, 0, stream>>>(hc, hf, cnt);
    hist_build<<<64, 256, 0, stream>>>(scores, hc);
    find_coarse<<<1, 1024, 0, stream>>>(hc, tb);
    hist_fine<<<64, 256, 0, stream>>>(scores, tb, hf);
    find_fine<<<1, 1024, 0, stream>>>(hf, tb, vlo);
    collect<<<200, 256, 0, stream>>>(scores, vlo, cidx, cnt);
    rescore<<<CAP, 256, 0, stream>>>(queries, affine, keys, cidx, cnt, resc);
    final_select<<<1, 256, 0, stream>>>(cidx, resc, cnt, values, out);
}